// Round 4
// baseline (490.238 us; speedup 1.0000x reference)
//
#include <hip/hip_runtime.h>

typedef _Float16 half8 __attribute__((ext_vector_type(8)));
typedef float floatx16 __attribute__((ext_vector_type(16)));

// x[16,3,32,128,128] f32 -> Conv3d(3->24,k=3,VALID) -> +bias -> min over depth -> softmax(co)
// out [16,24,1,126,126] f32
//
// Direct-conv MFMA: v_mfma_f32_32x32x16_f16, M=32 w-positions, N=32 (24 co used),
// K=16 (k=ci*3+kh, 9 used), accumulate over kd,kw. fp16 inputs, fp32 MFMA accum.
// C/D register->(w,co) mapping is determined EMPIRICALLY in-kernel via two probe
// MFMAs (layout-self-calibrating), so no documented-layout assumption remains.

__global__ __launch_bounds__(512, 4)
void ModelNew_80908593922715_kernel(const float* __restrict__ x,
                                    const float* __restrict__ wt,
                                    const float* __restrict__ bias,
                                    float* __restrict__ out)
{
    __shared__ __align__(16) _Float16 XT[26112]; // 32 dd * 34 w * 24-half rows (48B stride) = 52224 B

    const int tid  = threadIdx.x;
    const int lane = tid & 63;
    const int wid  = tid >> 6;
    const int co   = lane & 31;   // B-operand N index (output channel)
    const int q    = lane >> 5;   // k-octet select

    const int h  = blockIdx.x >> 2;
    const int wq = blockIdx.x & 3;
    const int n  = blockIdx.y;
    const int W0 = wq * 32;

    // ---- B fragments (weights): B[k][co], k = ci*3+kh, zero for k>=9 or co>=24
    half8 Bf[3][3];
    #pragma unroll
    for (int kd = 0; kd < 3; ++kd) {
      #pragma unroll
      for (int kw = 0; kw < 3; ++kw) {
        half8 b;
        #pragma unroll
        for (int j = 0; j < 8; ++j) {
          int k = q*8 + j;
          float wv = 0.0f;
          if (co < 24 && k < 9)
            wv = wt[co*81 + (k/3)*27 + kd*9 + (k%3)*3 + kw];
          b[j] = (_Float16)wv;
        }
        Bf[kd][kw] = b;
      }
    }

    // ---- stage x slab -> XT (f32 -> f16); halfs 0..15 of each row fully
    // written (zeros for k>=9 and for out-of-range w) so no garbage is read.
    for (int e = tid; e < 8704; e += 512) {       // 8 kp * 32 dd * 34 w2
        int w2 = e % 34;
        int t  = e / 34;
        int dd = t & 31;
        int kp = t >> 5;                          // half-pair 0..7 -> k = 2kp, 2kp+1
        int gw = W0 + w2;
        int k0 = kp*2, k1 = kp*2 + 1;
        float f0 = 0.0f, f1 = 0.0f;
        if (gw < 128) {
            if (k0 < 9) f0 = x[((size_t)(n*3 + k0/3)*32 + dd)*16384 + (h + k0%3)*128 + gw];
            if (k1 < 9) f1 = x[((size_t)(n*3 + k1/3)*32 + dd)*16384 + (h + k1%3)*128 + gw];
        }
        union { _Float16 hh[2]; unsigned int u; } pk;
        pk.hh[0] = (_Float16)f0;
        pk.hh[1] = (_Float16)f1;
        *(unsigned int*)((char*)XT + (size_t)(dd*34 + w2)*48 + kp*4) = pk.u;
    }
    __syncthreads();

    const char* xt = (const char*)XT;
    const int lanebase = (lane & 31)*48 + q*16;

    auto ldfrag = [&](int dd, int kw) -> half8 {
        return *(const half8*)(xt + dd*1632 + kw*48 + lanebase); // 1632 = 34*48
    };

    floatx16 macc;
    #pragma unroll
    for (int i = 0; i < 16; ++i) macc[i] = 3.0e38f;

    int d0, cnt;
    if (wid < 6) { d0 = wid*4;          cnt = 4; }
    else         { d0 = 24 + (wid-6)*3; cnt = 3; }

    auto pairbody = [&](int d) {
        floatx16 a0{}, a1{};
        #pragma unroll
        for (int ddo = 0; ddo < 4; ++ddo) {
          #pragma unroll
          for (int kw = 0; kw < 3; ++kw) {
            half8 f = ldfrag(d + ddo, kw);
            if (ddo < 3) a0 = __builtin_amdgcn_mfma_f32_32x32x16_f16(f, Bf[ddo][kw],   a0, 0, 0, 0);
            if (ddo > 0) a1 = __builtin_amdgcn_mfma_f32_32x32x16_f16(f, Bf[ddo-1][kw], a1, 0, 0, 0);
          }
        }
        #pragma unroll
        for (int i = 0; i < 16; ++i) macc[i] = fminf(macc[i], fminf(a0[i], a1[i]));
    };
    auto singlebody = [&](int d) {
        floatx16 a0{};
        #pragma unroll
        for (int ddo = 0; ddo < 3; ++ddo) {
          #pragma unroll
          for (int kw = 0; kw < 3; ++kw) {
            half8 f = ldfrag(d + ddo, kw);
            a0 = __builtin_amdgcn_mfma_f32_32x32x16_f16(f, Bf[ddo][kw], a0, 0, 0, 0);
          }
        }
        #pragma unroll
        for (int i = 0; i < 16; ++i) macc[i] = fminf(macc[i], a0[i]);
    };

    pairbody(d0);
    if (cnt == 4) pairbody(d0 + 2);
    else          singlebody(d0 + 2);

    // ---- probe the ACTUAL C/D layout: dw = 16*w(row), dc = 16*co(col) per (reg,lane)
    half8 pa, pone;
    #pragma unroll
    for (int j = 0; j < 8; ++j) { pa[j] = (_Float16)(float)co; pone[j] = (_Float16)1.0f; }
    floatx16 dwp{}, dcp{};
    dwp = __builtin_amdgcn_mfma_f32_32x32x16_f16(pa,   pone, dwp, 0, 0, 0);
    dcp = __builtin_amdgcn_mfma_f32_32x32x16_f16(pone, pa,   dcp, 0, 0, 0);

    // ---- cross-wave min via LDS (layout-agnostic: same (reg,lane) slot across waves)
    __syncthreads();
    float* xbuf = (float*)XT;                     // 8 waves * 16 regs * 64 lanes = 32 KB
    #pragma unroll
    for (int r = 0; r < 16; ++r)
        xbuf[(wid*16 + r)*64 + lane] = macc[r];
    __syncthreads();

    // ---- scatter min-conv values to vbuf[w][co] using the probed mapping
    float* vbuf = xbuf + 8192;                    // 32*32 floats at byte 32768
    #pragma unroll
    for (int rr = 0; rr < 2; ++rr) {
        int r = wid*2 + rr;                       // this wave finishes 2 of 16 regs
        float v = xbuf[r*64 + lane];
        #pragma unroll
        for (int w8 = 1; w8 < 8; ++w8)
            v = fminf(v, xbuf[(w8*16 + r)*64 + lane]);
        float dwv = 0.0f, dcv = 0.0f;
        #pragma unroll
        for (int rx = 0; rx < 16; ++rx)
            if (rx == r) { dwv = dwp[rx]; dcv = dcp[rx]; }  // static extracts + selects
        int wm = (int)(dwv * 0.0625f + 0.5f);
        int cm = (int)(dcv * 0.0625f + 0.5f);
        vbuf[wm*32 + cm] = v;
    }
    __syncthreads();

    // ---- softmax over channels with explicit indices: half-wave = one w, lane = co
    #pragma unroll
    for (int iter = 0; iter < 2; ++iter) {
        int w = wid*4 + q*2 + iter;               // 0..31
        int c = lane & 31;
        float val = (c < 24) ? (vbuf[w*32 + c] + bias[c]) : -3.0e38f;
        float mx = val;
        mx = fmaxf(mx, __shfl_xor(mx, 16, 64));
        mx = fmaxf(mx, __shfl_xor(mx,  8, 64));
        mx = fmaxf(mx, __shfl_xor(mx,  4, 64));
        mx = fmaxf(mx, __shfl_xor(mx,  2, 64));
        mx = fmaxf(mx, __shfl_xor(mx,  1, 64));
        float p = (c < 24) ? __expf(val - mx) : 0.0f;
        float s = p;
        s += __shfl_xor(s, 16, 64);
        s += __shfl_xor(s,  8, 64);
        s += __shfl_xor(s,  4, 64);
        s += __shfl_xor(s,  2, 64);
        s += __shfl_xor(s,  1, 64);
        int w_out = W0 + w;
        if (c < 24 && w_out < 126)
            out[(((size_t)n*24 + c)*126 + h)*126 + w_out] = p / s;
    }
}

extern "C" void kernel_launch(void* const* d_in, const int* in_sizes, int n_in,
                              void* d_out, int out_size, void* d_ws, size_t ws_size,
                              hipStream_t stream) {
    const float* x  = (const float*)d_in[0];
    const float* wt = (const float*)d_in[1];
    const float* bs = (const float*)d_in[2];
    float* out = (float*)d_out;

    dim3 grid(504, 16, 1); // (h*4 + wq) x n
    hipLaunchKernelGGL(ModelNew_80908593922715_kernel, grid, dim3(512, 1, 1), 0, stream,
                       x, wt, bs, out);
}

// Round 5
// 383.967 us; speedup vs baseline: 1.2768x; 1.2768x over previous
//
#include <hip/hip_runtime.h>

typedef _Float16 half8 __attribute__((ext_vector_type(8)));
typedef float floatx16 __attribute__((ext_vector_type(16)));

// x[16,3,32,128,128] f32 -> Conv3d(3->24,k=3,VALID) -> +bias -> min over depth -> softmax(co)
// out [16,24,1,126,126] f32
//
// v_mfma_f32_32x32x16_f16: M=32 w-positions, N=32 (24 co used), K=16 (k=ci*3+kh, 9 used),
// accumulated over kd,kw. fp16 in, f32 MFMA accum. C/D layout self-calibrated in the PREP
// kernel (probe MFMAs -> u16 index table in ws), B-fragments also prepacked in ws.

#define WS_IDX_OFF 0      // 2048 B: u16 idx[16][64] = wm*32+cm
#define WS_BF_OFF  2048   // 9216 B: half8 Bf[9][64]

__global__ void ModelNew_80908593922715_prep(const float* __restrict__ wt,
                                             void* __restrict__ ws)
{
    const int lane = threadIdx.x;            // 0..63
    const int co = lane & 31, q = lane >> 5;
    const int b  = blockIdx.x;               // 0..8 = kd*3+kw
    const int kd = b / 3, kw = b % 3;

    half8 bf;
    #pragma unroll
    for (int j = 0; j < 8; ++j) {
        int k = q*8 + j;
        float wv = 0.0f;
        if (co < 24 && k < 9)
            wv = wt[co*81 + (k/3)*27 + kd*9 + (k%3)*3 + kw];
        bf[j] = (_Float16)wv;
    }
    *(half8*)((char*)ws + WS_BF_OFF + (size_t)(b*64 + lane)*16) = bf;

    if (b == 0) {
        // probe ACTUAL C/D layout: dwp = 16*row(w), dcp = 16*col(co)
        half8 pa, pone;
        #pragma unroll
        for (int j = 0; j < 8; ++j) { pa[j] = (_Float16)(float)co; pone[j] = (_Float16)1.0f; }
        floatx16 dwp{}, dcp{};
        dwp = __builtin_amdgcn_mfma_f32_32x32x16_f16(pa,   pone, dwp, 0, 0, 0);
        dcp = __builtin_amdgcn_mfma_f32_32x32x16_f16(pone, pa,   dcp, 0, 0, 0);
        unsigned short* idx = (unsigned short*)((char*)ws + WS_IDX_OFF);
        #pragma unroll
        for (int r = 0; r < 16; ++r) {
            int wm = (int)(dwp[r] * 0.0625f + 0.5f);
            int cm = (int)(dcp[r] * 0.0625f + 0.5f);
            idx[r*64 + lane] = (unsigned short)(wm*32 + cm);
        }
    }
}

__global__ __launch_bounds__(512, 6)
void ModelNew_80908593922715_kernel(const float* __restrict__ x,
                                    const float* __restrict__ bias,
                                    const void* __restrict__ ws,
                                    float* __restrict__ out)
{
    __shared__ __align__(16) _Float16 XT[26112]; // 1088 rows (dd*34+w2) x 48 B

    const int tid  = threadIdx.x;
    const int lane = tid & 63;
    const int wid  = tid >> 6;
    const int q    = lane >> 5;

    const int h  = blockIdx.x >> 2;
    const int wq = blockIdx.x & 3;
    const int n  = blockIdx.y;
    const int W0 = wq * 32;

    // ---- prefetch constants from ws (L2-resident, coalesced)
    const char* wsB = (const char*)ws + WS_BF_OFF;
    half8 Bf[3][3];
    #pragma unroll
    for (int kd = 0; kd < 3; ++kd)
      #pragma unroll
      for (int kw = 0; kw < 3; ++kw)
        Bf[kd][kw] = *(const half8*)(wsB + (size_t)(((kd*3+kw)*64) + lane)*16);

    const unsigned short* idxT = (const unsigned short*)((const char*)ws + WS_IDX_OFF);
    const unsigned short ic0 = idxT[(wid*2 + 0)*64 + lane];
    const unsigned short ic1 = idxT[(wid*2 + 1)*64 + lane];
    float bco = 0.0f;
    if ((lane & 31) < 24) bco = bias[lane & 31];

    // ---- stage x slab -> XT: task f = dd*34 + w2; 9 f32 loads, 2x ds_write_b128
    const float* xb = x + (size_t)n*3*32*16384 + h*128 + W0;
    int w2 = tid % 34;
    int dd = tid / 34;
    int f  = tid;
    while (f < 1088) {
        const bool ok = (W0 + w2) < 128;
        const int boff = ok ? (dd*16384 + w2) : 0;
        float v0 = xb[boff];               // (ci,kh) plane offsets are compile-time
        float v1 = xb[boff + 128];
        float v2 = xb[boff + 256];
        float v3 = xb[boff + 524288];
        float v4 = xb[boff + 524416];
        float v5 = xb[boff + 524544];
        float v6 = xb[boff + 1048576];
        float v7 = xb[boff + 1048704];
        float v8 = xb[boff + 1048832];
        if (!ok) { v0=v1=v2=v3=v4=v5=v6=v7=v8=0.0f; }
        half8 h0, h1 = {};
        h0[0]=(_Float16)v0; h0[1]=(_Float16)v1; h0[2]=(_Float16)v2; h0[3]=(_Float16)v3;
        h0[4]=(_Float16)v4; h0[5]=(_Float16)v5; h0[6]=(_Float16)v6; h0[7]=(_Float16)v7;
        h1[0]=(_Float16)v8;                     // halfs 9..15 = 0 (K pad)
        char* rowp = (char*)XT + (size_t)(dd*34 + w2)*48;
        *(half8*)(rowp)      = h0;
        *(half8*)(rowp + 16) = h1;
        f += 512; w2 += 2; dd += 15;
        if (w2 >= 34) { w2 -= 34; dd += 1; }
    }
    __syncthreads();

    // ---- conv + min over depth
    const char* xt = (const char*)XT;
    const int lanebase = (lane & 31)*48 + q*16;

    floatx16 macc;
    #pragma unroll
    for (int i = 0; i < 16; ++i) macc[i] = 3.0e38f;

    int d0, cnt;
    if (wid < 6) { d0 = wid*4;          cnt = 4; }
    else         { d0 = 24 + (wid-6)*3; cnt = 3; }

    for (int dci = 0; dci < cnt; ++dci) {
        const char* xd = xt + (size_t)(d0 + dci)*1632 + lanebase; // 1632 = 34*48
        floatx16 a0{};
        #pragma unroll
        for (int kd = 0; kd < 3; ++kd)
          #pragma unroll
          for (int kw = 0; kw < 3; ++kw) {
            half8 fA = *(const half8*)(xd + kd*1632 + kw*48);
            a0 = __builtin_amdgcn_mfma_f32_32x32x16_f16(fA, Bf[kd][kw], a0, 0, 0, 0);
          }
        #pragma unroll
        for (int i = 0; i < 16; ++i) macc[i] = fminf(macc[i], a0[i]);
    }

    // ---- cross-wave min via LDS (same (reg,lane) slot across waves)
    __syncthreads();
    float* xbuf = (float*)XT;                  // 8 waves * 16 regs * 64 lanes = 32 KB
    #pragma unroll
    for (int r = 0; r < 16; ++r)
        xbuf[(wid*16 + r)*64 + lane] = macc[r];
    __syncthreads();

    // ---- scatter to vbuf[w][co] via precomputed probe indices
    float* vbuf = xbuf + 8192;                 // 32*32 f32 at byte 32768
    #pragma unroll
    for (int rr = 0; rr < 2; ++rr) {
        int r = wid*2 + rr;
        float v = xbuf[r*64 + lane];
        #pragma unroll
        for (int w8 = 1; w8 < 8; ++w8)
            v = fminf(v, xbuf[(w8*16 + r)*64 + lane]);
        vbuf[rr == 0 ? ic0 : ic1] = v;
    }
    __syncthreads();

    // ---- softmax over channels: half-wave = one w, lane&31 = co
    #pragma unroll
    for (int iter = 0; iter < 2; ++iter) {
        int w = wid*4 + q*2 + iter;            // 0..31
        int c = lane & 31;
        float val = (c < 24) ? (vbuf[w*32 + c] + bco) : -3.0e38f;
        float mx = val;
        mx = fmaxf(mx, __shfl_xor(mx, 16, 64));
        mx = fmaxf(mx, __shfl_xor(mx,  8, 64));
        mx = fmaxf(mx, __shfl_xor(mx,  4, 64));
        mx = fmaxf(mx, __shfl_xor(mx,  2, 64));
        mx = fmaxf(mx, __shfl_xor(mx,  1, 64));
        float p = (c < 24) ? __expf(val - mx) : 0.0f;
        float s = p;
        s += __shfl_xor(s, 16, 64);
        s += __shfl_xor(s,  8, 64);
        s += __shfl_xor(s,  4, 64);
        s += __shfl_xor(s,  2, 64);
        s += __shfl_xor(s,  1, 64);
        int w_out = W0 + w;
        if (c < 24 && w_out < 126)
            out[(((size_t)n*24 + c)*126 + h)*126 + w_out] = p / s;
    }
}

extern "C" void kernel_launch(void* const* d_in, const int* in_sizes, int n_in,
                              void* d_out, int out_size, void* d_ws, size_t ws_size,
                              hipStream_t stream) {
    const float* x  = (const float*)d_in[0];
    const float* wt = (const float*)d_in[1];
    const float* bs = (const float*)d_in[2];
    float* out = (float*)d_out;

    hipLaunchKernelGGL(ModelNew_80908593922715_prep, dim3(9), dim3(64), 0, stream,
                       wt, d_ws);
    hipLaunchKernelGGL(ModelNew_80908593922715_kernel, dim3(504, 16), dim3(512), 0, stream,
                       x, bs, d_ws, out);
}